// Round 7
// baseline (97.140 us; speedup 1.0000x reference)
//
#include <hip/hip_runtime.h>

#define B 8
#define NH 512
#define D 128
#define HEADS 4
#define ALPHA 0.2f

typedef short short8 __attribute__((ext_vector_type(8)));
typedef float f32x4 __attribute__((ext_vector_type(4)));
typedef unsigned short u16t;

__device__ __forceinline__ unsigned short f2b(float f) {
    union { float f; unsigned u; } v; v.f = f;
    unsigned r = v.u + 0x7FFFu + ((v.u >> 16) & 1u);
    return (unsigned short)(r >> 16);
}
__device__ __forceinline__ float lrelu(float x) { return fmaxf(x, ALPHA * x); }
// pack two f32 -> two bf16 (truncation) in one v_perm
__device__ __forceinline__ unsigned packbf(float a, float b) {
    union { float f; unsigned u; } ua, ub; ua.f = a; ub.f = b;
    return __builtin_amdgcn_perm(ub.u, ua.u, 0x07060302u);
}
// pack two f32 -> two bf16 with RNE rounding (matches f2b)
__device__ __forceinline__ unsigned packbf_rne(float a, float b) {
    return (unsigned)f2b(a) | ((unsigned)f2b(b) << 16);
}

// ============ proj1: h1T[bh][c][n] = (x @ Wh)^T, + f1a/f2a =================
// grid 512 (128 row-tiles of 64 x 4 heads), 256 thr.
// Side-jobs: bid<128 emit WoT[c][k]=bf16(Wo[k][c]); all blocks zero h2acc.
__global__ __launch_bounds__(256) void proj1_kernel(
    const float* __restrict__ hs, const float* __restrict__ os,
    const float* __restrict__ Wh, const float* __restrict__ Wo,
    const float* __restrict__ ah,
    u16t* __restrict__ h1T, u16t* __restrict__ WoT,
    float* __restrict__ f1, float* __restrict__ f2,
    float* __restrict__ h2acc)
{
    int bid = blockIdx.x;
    int rt = bid >> 2, h = bid & 3;
    int rowG = rt * 64;
    int b = rowG >> 10;
    int t = threadIdx.x;
    int w = t >> 6, l = t & 63, l15 = l & 15, g = l >> 4;

    __shared__ __align__(16) u16t wlds[128][136];   // [c][k], pad 8

    // zero h2acc slice: 1,048,576 f32 / 512 blocks = 2048 per block
    {
        float4 z4 = {0.f, 0.f, 0.f, 0.f};
        float* dst = h2acc + (size_t)bid * 2048 + t * 8;
        *(float4*)dst = z4;
        *(float4*)(dst + 4) = z4;
    }

    // stage W[h]^T into LDS
    {
        const float* Whh = Wh + (size_t)h * 16384;
        #pragma unroll
        for (int i = 0; i < 32; ++i) {
            int p = i * 256 + t;
            int c = p & 127, k0 = (p >> 7) * 2;
            float w0 = Whh[(size_t)k0 * 128 + c];
            float w1 = Whh[(size_t)(k0 + 1) * 128 + c];
            *(unsigned*)&wlds[c][k0] = packbf_rne(w0, w1);
        }
    }
    // side job: emit WoT (128 blocks x 256 thr x 2 elems)
    if (bid < 128) {
        int idx = bid * 512 + t * 2;
        int c = idx >> 9, k = idx & 511;
        float w0 = Wo[(size_t)k * 128 + c];
        float w1 = Wo[(size_t)(k + 1) * 128 + c];
        *(unsigned*)&WoT[(size_t)c * 512 + k] = packbf_rne(w0, w1);
    }
    __syncthreads();

    int nA = rowG + w * 16 + l15;
    int nloc = nA & 1023;
    const float* xr = (nloc < NH) ? hs + ((size_t)(b * NH + nloc)) * 128
                                  : os + ((size_t)(b * NH + (nloc - NH))) * 128;

    f32x4 acc[8] = {};
    #pragma unroll
    for (int kc = 0; kc < 4; ++kc) {
        int k0 = kc * 32 + g * 8;
        float4 u0 = *(const float4*)&xr[k0];
        float4 u1 = *(const float4*)&xr[k0 + 4];
        union { unsigned u[4]; short8 s; } afu;
        afu.u[0] = packbf_rne(u0.x, u0.y);
        afu.u[1] = packbf_rne(u0.z, u0.w);
        afu.u[2] = packbf_rne(u1.x, u1.y);
        afu.u[3] = packbf_rne(u1.z, u1.w);
        short8 af = afu.s;
        #pragma unroll
        for (int ct = 0; ct < 8; ++ct) {
            short8 bfr = *(const short8*)&wlds[ct * 16 + l15][k0];
            acc[ct] = __builtin_amdgcn_mfma_f32_16x16x32_bf16(af, bfr, acc[ct], 0, 0, 0);
        }
    }

    int bh = b * HEADS + h;
    size_t hTbase = (size_t)bh * 131072;
    int nloc0 = (rowG & 1023) + w * 16 + g * 4;
    float pr1[4] = {0.f, 0.f, 0.f, 0.f}, pr2[4] = {0.f, 0.f, 0.f, 0.f};

    #pragma unroll
    for (int ct = 0; ct < 8; ++ct) {
        int c = ct * 16 + l15;
        unsigned long long pv =
              (unsigned long long)f2b(acc[ct][0])
            | ((unsigned long long)f2b(acc[ct][1]) << 16)
            | ((unsigned long long)f2b(acc[ct][2]) << 32)
            | ((unsigned long long)f2b(acc[ct][3]) << 48);
        *(unsigned long long*)&h1T[hTbase + (size_t)c * 1024 + nloc0] = pv;
        float a1 = ah[h * 256 + c], a2 = ah[h * 256 + 128 + c];
        #pragma unroll
        for (int r = 0; r < 4; ++r) {
            pr1[r] = fmaf(acc[ct][r], a1, pr1[r]);
            pr2[r] = fmaf(acc[ct][r], a2, pr2[r]);
        }
    }
    #pragma unroll
    for (int r = 0; r < 4; ++r) {
        float v1 = pr1[r], v2 = pr2[r];
        #pragma unroll
        for (int m = 1; m <= 8; m <<= 1) {
            v1 += __shfl_xor(v1, m, 64);
            v2 += __shfl_xor(v2, m, 64);
        }
        if (l15 == 0) {
            f1[(size_t)bh * 1024 + nloc0 + r] = v1;
            f2[(size_t)bh * 1024 + nloc0 + r] = v2;
        }
    }
}

// ============ attn0: O^T = H^T·P^T + fused proj2-partials via atomics ======
// 512 blocks (XCD-swizzled). No x2 store: epilogue runs the head-slice
// partial GEMM  h2acc[b][c][n] += WoT_h^T · x2tile^T  (f32 atomics).
__global__ __launch_bounds__(256) void attn0_kernel(
    const u16t* __restrict__ HT,                    // [Z][128][1024] bf16
    const float* __restrict__ f1, const float* __restrict__ f2,  // [Z][1024]
    const u16t* __restrict__ WoT,                   // [128][512] bf16
    float* __restrict__ h2acc)                      // [B][128][1024] f32
{
    __shared__ __align__(16) u16t hbuf[2][128][40];
    __shared__ __align__(16) u16t x2t[4][16][136];  // per-wave x2 tile [n][k]
    __shared__ __align__(16) float f2s[512];
    __shared__ float red4[4];

    int t = threadIdx.x, w4 = t >> 6, l = t & 63, l15 = l & 15, g = l >> 4;
    int wid = blockIdx.x;
    int xcd = wid & 7, jj = (wid >> 3) & 7;
    int itile = wid >> 6;
    int q = xcd * 8 + jj;
    int z = q >> 1, side = q & 1;
    int b = z >> 2, h = z & 3;
    bool self = (side == 0);
    int nbBase = self ? 512 : 0;
    size_t HTbase = (size_t)z * 131072;
    size_t fbase = (size_t)z * 1024;

    f2s[t] = f2[fbase + nbBase + t];
    f2s[t + 256] = f2[fbase + nbBase + t + 256];
    __syncthreads();
    float mv = fmaxf(f2s[t], f2s[t + 256]);
    #pragma unroll
    for (int m = 1; m <= 32; m <<= 1) mv = fmaxf(mv, __shfl_xor(mv, m, 64));
    if (l == 0) red4[w4] = mv;
    __syncthreads();
    float M = fmaxf(fmaxf(red4[0], red4[1]), fmaxf(red4[2], red4[3]));

    int i0 = itile * 64 + w4 * 16;
    int i = i0 + l15;
    int n = side * 512 + i;
    float fv = f1[fbase + n];
    float mr = lrelu(fv + M);
    float z0 = 0.f;
    if (self) {
        float sc = lrelu(fv + f2[fbase + i]);
        mr = fmaxf(mr, sc);
        z0 = __expf(sc - mr);
    }
    float zacc = (g == 0) ? z0 : 0.f;

    {
        int c = t >> 1, ks = (t & 1) * 16;
        const u16t* src = &HT[HTbase + (size_t)c * 1024 + nbBase + ks];
        *(short8*)&hbuf[0][c][ks] = *(const short8*)src;
        *(short8*)&hbuf[0][c][ks + 8] = *(const short8*)(src + 8);
    }
    __syncthreads();

    f32x4 acc[8] = {};
    int cS = t >> 1, ksS = (t & 1) * 16;

    for (int jt = 0; jt < 16; ++jt) {
        int cur = jt & 1;
        short8 s0, s1;
        if (jt < 15) {
            const u16t* src = &HT[HTbase + (size_t)cS * 1024 + nbBase + (jt + 1) * 32 + ksS];
            s0 = *(const short8*)src;
            s1 = *(const short8*)(src + 8);
        }
        int j0 = jt * 32 + g * 8;
        float p[8];
        #pragma unroll
        for (int qq = 0; qq < 8; ++qq) {
            float tq = fv + f2s[j0 + qq];
            float ev = fmaxf(tq, ALPHA * tq);
            p[qq] = __expf(ev - mr);
            zacc += p[qq];
        }
        union { unsigned u[4]; short8 s; } pfu;
        pfu.u[0] = packbf(p[0], p[1]);
        pfu.u[1] = packbf(p[2], p[3]);
        pfu.u[2] = packbf(p[4], p[5]);
        pfu.u[3] = packbf(p[6], p[7]);
        short8 pf = pfu.s;
        #pragma unroll
        for (int ct = 0; ct < 8; ++ct) {
            short8 hf = *(const short8*)&hbuf[cur][ct * 16 + l15][g * 8];
            acc[ct] = __builtin_amdgcn_mfma_f32_16x16x32_bf16(hf, pf, acc[ct], 0, 0, 0);
        }
        if (jt < 15) {
            *(short8*)&hbuf[cur ^ 1][cS][ksS] = s0;
            *(short8*)&hbuf[cur ^ 1][cS][ksS + 8] = s1;
        }
        __syncthreads();
    }

    // self-loop via diagonal-B MFMA
    if (self) {
        unsigned short z0b = f2b(z0);
        short8 pfs;
        #pragma unroll
        for (int qq = 0; qq < 8; ++qq)
            pfs[qq] = (short)((g * 8 + qq == l15) ? z0b : 0);
        int sc0 = side * 512 + i0;
        #pragma unroll
        for (int ct = 0; ct < 8; ++ct) {
            short8 hfs = *(const short8*)&HT[HTbase + (size_t)(ct * 16 + l15) * 1024 + sc0 + g * 8];
            acc[ct] = __builtin_amdgcn_mfma_f32_16x16x32_bf16(hfs, pfs, acc[ct], 0, 0, 0);
        }
    }

    zacc += __shfl_xor(zacc, 16, 64);
    zacc += __shfl_xor(zacc, 32, 64);
    float zinv = 1.f / zacc;

    // x2 tile (elu'd, bf16) -> wave-local LDS [n-row][k]
    #pragma unroll
    for (int ct = 0; ct < 8; ++ct) {
        float o[4];
        #pragma unroll
        for (int r = 0; r < 4; ++r) {
            float v = acc[ct][r] * zinv;
            o[r] = v > 0.f ? v : __expf(v) - 1.f;
        }
        unsigned long long pv =
              (unsigned long long)packbf_rne(o[0], o[1])
            | ((unsigned long long)packbf_rne(o[2], o[3]) << 32);
        *(unsigned long long*)&x2t[w4][l15][ct * 16 + g * 4] = pv;
    }

    // wave-local partial GEMM: A = WoT head-slice (c2 rows), B = x2t (n cols)
    f32x4 acc2[8] = {};
    const u16t* wop = WoT + h * 128;
    #pragma unroll
    for (int kc = 0; kc < 4; ++kc) {
        short8 bfr = *(const short8*)&x2t[w4][l15][kc * 32 + g * 8];
        #pragma unroll
        for (int ct2 = 0; ct2 < 8; ++ct2) {
            short8 af = *(const short8*)&wop[(size_t)(ct2 * 16 + l15) * 512 + kc * 32 + g * 8];
            acc2[ct2] = __builtin_amdgcn_mfma_f32_16x16x32_bf16(af, bfr, acc2[ct2], 0, 0, 0);
        }
    }
    // accumulate: C-frag lane l15 = n-col (coalesced), row = c2
    float* hp = h2acc + (size_t)b * 131072;
    #pragma unroll
    for (int ct2 = 0; ct2 < 8; ++ct2) {
        #pragma unroll
        for (int r = 0; r < 4; ++r) {
            int c2 = ct2 * 16 + g * 4 + r;
            atomicAdd(hp + (size_t)c2 * 1024 + n, acc2[ct2][r]);
        }
    }
}

// ============ attn1: humans attend objects+self over h2acc (f32) ===========
// 64 blocks (8 b x 8 itiles of 64). Prologue computes f1b/f2b via dots.
// Epilogue: elu + log_softmax -> d_out.
__global__ __launch_bounds__(256) void attn1_kernel(
    const float* __restrict__ h2acc,                // [B][128][1024] f32
    const float* __restrict__ ao,                   // [256]
    float* __restrict__ dout)
{
    __shared__ __align__(16) u16t hbuf[2][128][40];
    __shared__ __align__(16) float f2s[512];
    __shared__ float f1own[64], f2own[64];
    __shared__ float red4[4];

    int t = threadIdx.x, w4 = t >> 6, l = t & 63, l15 = l & 15, g = l >> 4;
    int b = blockIdx.x & 7, itile = blockIdx.x >> 3;
    const float* h2 = h2acc + (size_t)b * 131072;

    // rank-1 dots: f2 of objects (t, t+256), f1/f2 of own rows (t<64)
    {
        float s1 = 0.f, s2 = 0.f, p1 = 0.f, p2 = 0.f;
        int nown = itile * 64 + (t & 63);
        #pragma unroll 4
        for (int c = 0; c < 128; ++c) {
            float a1 = ao[c], a2 = ao[128 + c];
            const float* row = h2 + (size_t)c * 1024;
            s1 = fmaf(row[512 + t], a2, s1);
            s2 = fmaf(row[768 + t], a2, s2);
            if (t < 64) {
                float hv = row[nown];
                p1 = fmaf(hv, a1, p1);
                p2 = fmaf(hv, a2, p2);
            }
        }
        f2s[t] = s1;
        f2s[t + 256] = s2;
        if (t < 64) { f1own[t] = p1; f2own[t] = p2; }
        float mvv = fmaxf(s1, s2);
        #pragma unroll
        for (int m = 1; m <= 32; m <<= 1) mvv = fmaxf(mvv, __shfl_xor(mvv, m, 64));
        if (l == 0) red4[w4] = mvv;
    }
    __syncthreads();
    float M = fmaxf(fmaxf(red4[0], red4[1]), fmaxf(red4[2], red4[3]));

    int i0 = itile * 64 + w4 * 16;
    int i = i0 + l15;
    float fv = f1own[w4 * 16 + l15];
    float mr = lrelu(fv + M);
    float sc = lrelu(fv + f2own[w4 * 16 + l15]);
    mr = fmaxf(mr, sc);
    float z0 = __expf(sc - mr);
    float zacc = (g == 0) ? z0 : 0.f;

    // prologue: stage chunk 0 (f32 -> bf16)
    int cS = t >> 1, ksS = (t & 1) * 16;
    {
        const float* src = h2 + (size_t)cS * 1024 + 512 + ksS;
        float4 q0 = *(const float4*)(src + 0);
        float4 q1 = *(const float4*)(src + 4);
        float4 q2 = *(const float4*)(src + 8);
        float4 q3 = *(const float4*)(src + 12);
        union { unsigned u[8]; short8 s[2]; } pk;
        pk.u[0] = packbf_rne(q0.x, q0.y); pk.u[1] = packbf_rne(q0.z, q0.w);
        pk.u[2] = packbf_rne(q1.x, q1.y); pk.u[3] = packbf_rne(q1.z, q1.w);
        pk.u[4] = packbf_rne(q2.x, q2.y); pk.u[5] = packbf_rne(q2.z, q2.w);
        pk.u[6] = packbf_rne(q3.x, q3.y); pk.u[7] = packbf_rne(q3.z, q3.w);
        *(short8*)&hbuf[0][cS][ksS] = pk.s[0];
        *(short8*)&hbuf[0][cS][ksS + 8] = pk.s[1];
    }
    __syncthreads();

    f32x4 acc[8] = {};

    for (int jt = 0; jt < 16; ++jt) {
        int cur = jt & 1;
        float4 q0, q1, q2, q3;
        if (jt < 15) {
            const float* src = h2 + (size_t)cS * 1024 + 512 + (jt + 1) * 32 + ksS;
            q0 = *(const float4*)(src + 0);
            q1 = *(const float4*)(src + 4);
            q2 = *(const float4*)(src + 8);
            q3 = *(const float4*)(src + 12);
        }
        int j0 = jt * 32 + g * 8;
        float p[8];
        #pragma unroll
        for (int qq = 0; qq < 8; ++qq) {
            float tq = fv + f2s[j0 + qq];
            float ev = fmaxf(tq, ALPHA * tq);
            p[qq] = __expf(ev - mr);
            zacc += p[qq];
        }
        union { unsigned u[4]; short8 s; } pfu;
        pfu.u[0] = packbf(p[0], p[1]);
        pfu.u[1] = packbf(p[2], p[3]);
        pfu.u[2] = packbf(p[4], p[5]);
        pfu.u[3] = packbf(p[6], p[7]);
        short8 pf = pfu.s;
        #pragma unroll
        for (int ct = 0; ct < 8; ++ct) {
            short8 hf = *(const short8*)&hbuf[cur][ct * 16 + l15][g * 8];
            acc[ct] = __builtin_amdgcn_mfma_f32_16x16x32_bf16(hf, pf, acc[ct], 0, 0, 0);
        }
        if (jt < 15) {
            union { unsigned u[8]; short8 s[2]; } pk;
            pk.u[0] = packbf_rne(q0.x, q0.y); pk.u[1] = packbf_rne(q0.z, q0.w);
            pk.u[2] = packbf_rne(q1.x, q1.y); pk.u[3] = packbf_rne(q1.z, q1.w);
            pk.u[4] = packbf_rne(q2.x, q2.y); pk.u[5] = packbf_rne(q2.z, q2.w);
            pk.u[6] = packbf_rne(q3.x, q3.y); pk.u[7] = packbf_rne(q3.z, q3.w);
            *(short8*)&hbuf[cur ^ 1][cS][ksS] = pk.s[0];
            *(short8*)&hbuf[cur ^ 1][cS][ksS + 8] = pk.s[1];
        }
        __syncthreads();
    }

    // self-loop diagonal MFMA, fragments from h2acc f32
    {
        unsigned short z0b = f2b(z0);
        short8 pfs;
        #pragma unroll
        for (int qq = 0; qq < 8; ++qq)
            pfs[qq] = (short)((g * 8 + qq == l15) ? z0b : 0);
        #pragma unroll
        for (int ct = 0; ct < 8; ++ct) {
            const float* src = h2 + (size_t)(ct * 16 + l15) * 1024 + i0 + g * 8;
            float4 q0 = *(const float4*)(src + 0);
            float4 q1 = *(const float4*)(src + 4);
            union { unsigned u[4]; short8 s; } pk;
            pk.u[0] = packbf_rne(q0.x, q0.y); pk.u[1] = packbf_rne(q0.z, q0.w);
            pk.u[2] = packbf_rne(q1.x, q1.y); pk.u[3] = packbf_rne(q1.z, q1.w);
            acc[ct] = __builtin_amdgcn_mfma_f32_16x16x32_bf16(pk.s, pfs, acc[ct], 0, 0, 0);
        }
    }

    zacc += __shfl_xor(zacc, 16, 64);
    zacc += __shfl_xor(zacc, 32, 64);
    float zinv = 1.f / zacc;

    float o[8][4];
    float mx = -3.0e38f;
    #pragma unroll
    for (int ct = 0; ct < 8; ++ct) {
        #pragma unroll
        for (int r = 0; r < 4; ++r) {
            float v = acc[ct][r] * zinv;
            v = v > 0.f ? v : __expf(v) - 1.f;
            o[ct][r] = v;
            mx = fmaxf(mx, v);
        }
    }
    mx = fmaxf(mx, __shfl_xor(mx, 16, 64));
    mx = fmaxf(mx, __shfl_xor(mx, 32, 64));
    float s = 0.f;
    #pragma unroll
    for (int ct = 0; ct < 8; ++ct)
        #pragma unroll
        for (int r = 0; r < 4; ++r) s += __expf(o[ct][r] - mx);
    s += __shfl_xor(s, 16, 64);
    s += __shfl_xor(s, 32, 64);
    float lse = mx + __logf(s);
    #pragma unroll
    for (int ct = 0; ct < 8; ++ct) {
        float4 st = {o[ct][0] - lse, o[ct][1] - lse, o[ct][2] - lse, o[ct][3] - lse};
        *(float4*)&dout[((size_t)(b * 512 + i)) * 128 + ct * 16 + g * 4] = st;
    }
}

extern "C" void kernel_launch(void* const* d_in, const int* in_sizes, int n_in,
                              void* d_out, int out_size, void* d_ws, size_t ws_size,
                              hipStream_t stream)
{
    const float* hs = (const float*)d_in[0];
    const float* os = (const float*)d_in[1];
    const float* Wh = (const float*)d_in[4];
    const float* ah = (const float*)d_in[5];
    const float* Wo = (const float*)d_in[6];
    const float* ao = (const float*)d_in[7];
    float* out = (float*)d_out;

    u16t* h1T = (u16t*)d_ws;              // 4,194,304 u16
    u16t* WoT = h1T + 4194304;            // 65,536 u16
    float* h2acc = (float*)(WoT + 65536); // 1,048,576 f32
    float* f1a = h2acc + 1048576;         // 32,768 f32
    float* f2a = f1a + 32768;             // 32,768 f32

    proj1_kernel<<<512, 256, 0, stream>>>(hs, os, Wh, Wo, ah, h1T, WoT, f1a, f2a, h2acc);
    attn0_kernel<<<512, 256, 0, stream>>>(h1T, f1a, f2a, WoT, h2acc);
    attn1_kernel<<<64, 256, 0, stream>>>(h2acc, ao, out);
}